// Round 6
// baseline (839.648 us; speedup 1.0000x reference)
//
#include <hip/hip_runtime.h>

#define B_      2
#define NSU     2076
#define NSV     8940
#define ROWS_SU (B_ * NSU)            // 4152
#define ROWS_ALL (B_ * (NSU + NSV))   // 22032
#define MP_SU   2176
#define MP_SV   8960
#define NB64_SV 140                   // 8960/64
#define NB64_SU 33                    // 2112/64
#define NBX     (2 * NB64_SV + 2 * NB64_SU)   // 346
#define NH      4                     // K-split factor
#define KQ_SV   2240                  // conv2p k-cols per split (64-mult)
#define KQ_SU   512
#define KE_SV   8960
#define KE_SU   2112
#define T_SV    560                   // 16-row tiles per solvent batch
#define T_SU    132
#define TILES_TOT (2 * T_SV + 2 * T_SU)   // 1384
#define PADROWS (TILES_TOT * 16)          // 22144
#define TSZ_SV  ((size_t)16 * MP_SV)      // 143360 elems per sv tile
#define TSZ_SU  ((size_t)16 * MP_SU)      // 33792 elems per su tile
#define SU_BASE_E ((size_t)2 * T_SV * TSZ_SV)
#define NEG_INF (-3.402823466e38f)

typedef __attribute__((ext_vector_type(8))) short bf16x8;
typedef __attribute__((ext_vector_type(8))) unsigned short u16x8;
typedef __attribute__((ext_vector_type(4))) float f32x4;

#define MFMA16 __builtin_amdgcn_mfma_f32_16x16x32_bf16

__device__ __forceinline__ unsigned short f2bf(float x) {
    unsigned int u = __float_as_uint(x);
    u += 0x7FFFu + ((u >> 16) & 1u);
    return (unsigned short)(u >> 16);
}
__device__ __forceinline__ unsigned int pkbf(float lo, float hi) {
    unsigned int r;
    asm("v_cvt_pk_bf16_f32 %0, %1, %2" : "=v"(r) : "v"(lo), "v"(hi));
    return r;
}

// ---------------- pre: y1t = (x @ W_c1)^T bf16 ; init = x @ W_fc1 + b_fc1 ----------------
__global__ __launch_bounds__(256) void pre_kernel(
    const float* __restrict__ xsu, const float* __restrict__ xsv,
    const float* __restrict__ Wc1, const float* __restrict__ Wfc1,
    const float* __restrict__ bfc1,
    unsigned short* __restrict__ y1t, float* __restrict__ initb)
{
    __shared__ float sWc1[64 * 64];
    __shared__ float sWfc1[64 * 32];
    __shared__ float sb[32];
    const int tid = threadIdx.x;
    for (int i = tid; i < 64 * 64; i += 256) sWc1[i] = Wc1[i];
    for (int i = tid; i < 64 * 32; i += 256) sWfc1[i] = Wfc1[i];
    if (tid < 32) sb[tid] = bfc1[tid];
    __syncthreads();

    const int rid = blockIdx.x * 256 + tid;
    if (rid >= ROWS_ALL) return;

    const float* xrow; unsigned short* yt; int m; size_t MPl;
    if (rid < ROWS_SU) {
        int b = rid / NSU; m = rid - b * NSU;
        xrow = xsu + (size_t)rid * 64;
        yt = y1t + (size_t)b * 64 * MP_SU; MPl = MP_SU;
    } else {
        int r2 = rid - ROWS_SU;
        int b = r2 / NSV; m = r2 - b * NSV;
        xrow = xsv + (size_t)r2 * 64;
        yt = y1t + (size_t)2 * 64 * MP_SU + (size_t)b * 64 * MP_SV; MPl = MP_SV;
    }

    float xr[64];
    #pragma unroll
    for (int f4 = 0; f4 < 16; ++f4) {
        float4 v = ((const float4*)xrow)[f4];
        xr[f4 * 4 + 0] = v.x; xr[f4 * 4 + 1] = v.y;
        xr[f4 * 4 + 2] = v.z; xr[f4 * 4 + 3] = v.w;
    }
    for (int c = 0; c < 64; ++c) {
        float acc = 0.f;
        #pragma unroll
        for (int f = 0; f < 64; ++f) acc += xr[f] * sWc1[f * 64 + c];
        yt[(size_t)c * MPl + m] = f2bf(acc);
    }
    float* ini = initb + (size_t)rid * 32;
    for (int c = 0; c < 32; ++c) {
        float acc = sb[c];
        #pragma unroll
        for (int f = 0; f < 64; ++f) acc += xr[f] * sWfc1[f * 32 + c];
        ini[c] = acc;
    }
}

// ---------------- conv1f: fused dense-read conv1 + bf16 fragment-layout writeback --------
// Block = 64 rows x 64 cols for one k-range. Staging: wave w reads rows of tile w as
// DENSE 1KB row-chunks (fp32), cvt to bf16, -> LDS fragment layout (XOR-swizzled) and
// -> abft global (linear fragment layout). Compute: wave w = col-group w; A-frags from
// LDS (shared across waves), B from L2-resident y1t; accumulate p1 partials.
__global__ __launch_bounds__(256) void conv1f_kernel(
    const float* __restrict__ adj_su, const float* __restrict__ adj_sv,
    const unsigned short* __restrict__ y1t,
    unsigned short* __restrict__ abft,
    float* __restrict__ p1)
{
    __shared__ unsigned short ALDS[16384];   // [tile4][j4][unit128][8] = 32KB
    const int bid = blockIdx.x, q = blockIdx.y;
    const int tid = threadIdx.x, lane = tid & 63, w = tid >> 6;
    const int l15 = lane & 15, kq = lane >> 4;

    int M, MP, row0, tile0, kbeg, kend;
    const float* A; const unsigned short* Yt; unsigned short* AbW;
    if (bid < 2 * NB64_SV) {
        int b = bid / NB64_SV, rb = bid - b * NB64_SV;
        M = NSV; MP = MP_SV;
        kbeg = q * 2304; kend = (q == 3) ? MP_SV : (kbeg + 2304);
        A  = adj_sv + (size_t)b * NSV * NSV;
        Yt = y1t + (size_t)2 * 64 * MP_SU + (size_t)b * 64 * MP_SV;
        row0 = rb * 64; tile0 = b * T_SV + rb * 4;
        AbW = abft + (size_t)(tile0 + w) * TSZ_SV;
    } else {
        int t = bid - 2 * NB64_SV;
        int b = t / NB64_SU, rb = t - b * NB64_SU;
        M = NSU; MP = MP_SU;
        kbeg = (q == 0) ? 0 : (q == 1) ? 768 : (q == 2) ? 1280 : 1792;
        kend = (q == 0) ? 768 : (q == 1) ? 1280 : (q == 2) ? 1792 : 2176;
        A  = adj_su + (size_t)b * NSU * NSU;
        Yt = y1t + (size_t)b * 64 * MP_SU;
        row0 = rb * 64;
        int tsu = b * T_SU + rb * 4;
        tile0 = 2 * T_SV + tsu;
        AbW = abft + SU_BASE_E + (size_t)(tsu + w) * TSZ_SU;
    }

    const unsigned short* BpW = Yt + (size_t)(w * 16 + l15) * MP + kq * 8;

    f32x4 acc0 = {0.f,0.f,0.f,0.f}, acc1 = acc0, acc2 = acc0, acc3 = acc0;

    // staging lane constants
    const int scol_off = lane * 4;              // col = kc + scol_off
    const int sj    = scol_off >> 6;            // 0..3
    const int shalf = (scol_off >> 5) & 1;
    const int scg   = (scol_off >> 3) & 3;
    const int se    = scol_off & 7;             // 0 or 4
    const int sxor  = scg ^ (shalf << 2);
    const int subase = shalf * 64 + scg * 16;   // + i = unit

    for (int kc = kbeg; kc < kend; kc += 256) {
        const int kc2 = min(kc + 256, kend);
        const int nj = (kc2 - kc) >> 6;
        // ---- stage: 16 dense 1KB row reads per wave ----
        if (scol_off < kc2 - kc) {
            const int col = kc + scol_off;
            const bool inM = col < M;           // M%4==0, col 4-aligned
            const size_t ck1024 = (size_t)((kc >> 6) + sj) * 1024;
            unsigned short* lbase = &ALDS[((w * 4 + sj) * 128) * 8];
            #pragma unroll
            for (int i = 0; i < 16; ++i) {
                const int r = row0 + w * 16 + i;
                const float* Ar = A + (size_t)((r < M) ? r : (M - 1)) * M;
                float4 v = make_float4(0.f, 0.f, 0.f, 0.f);
                if (inM) v = *(const float4*)(Ar + col);
                const unsigned int u0 = pkbf(v.x, v.y);
                const unsigned int u1 = pkbf(v.z, v.w);
                const int unit = subase + i;
                unsigned short* lp = lbase + (size_t)((unit ^ sxor) * 8 + se);
                *(unsigned int*)lp = u0;
                *(unsigned int*)(lp + 2) = u1;
                *(uint2*)(AbW + ck1024 + unit * 8 + se) = make_uint2(u0, u1);
            }
        }
        __syncthreads();
        // ---- compute: 4 tiles x nj k64 x 2 k32 MFMAs ----
        #pragma unroll
        for (int j = 0; j < 4; ++j) {
            if (j < nj) {
                #pragma unroll
                for (int half = 0; half < 2; ++half) {
                    bf16x8 bfrag = *(const bf16x8*)(BpW + (kc + j * 64 + half * 32));
                    const int unit = half * 64 + kq * 16 + l15;
                    const int swz = unit ^ kq ^ (half << 2);
                    const bf16x8* a0p = (const bf16x8*)&ALDS[((0 * 4 + j) * 128 + swz) * 8];
                    const bf16x8* a1p = (const bf16x8*)&ALDS[((1 * 4 + j) * 128 + swz) * 8];
                    const bf16x8* a2p = (const bf16x8*)&ALDS[((2 * 4 + j) * 128 + swz) * 8];
                    const bf16x8* a3p = (const bf16x8*)&ALDS[((3 * 4 + j) * 128 + swz) * 8];
                    acc0 = MFMA16(*a0p, bfrag, acc0, 0, 0, 0);
                    acc1 = MFMA16(*a1p, bfrag, acc1, 0, 0, 0);
                    acc2 = MFMA16(*a2p, bfrag, acc2, 0, 0, 0);
                    acc3 = MFMA16(*a3p, bfrag, acc3, 0, 0, 0);
                }
            }
        }
        __syncthreads();
    }

    // epilogue: p1[q][tile0+t][row16][col64]; C/D: col=l15(within wave group), row=kq*4+j
    #pragma unroll
    for (int j = 0; j < 4; ++j) {
        const int r = kq * 4 + j;
        const int c = w * 16 + l15;
        p1[((size_t)q * TILES_TOT + tile0 + 0) * 1024 + r * 64 + c] = acc0[j];
        p1[((size_t)q * TILES_TOT + tile0 + 1) * 1024 + r * 64 + c] = acc1[j];
        p1[((size_t)q * TILES_TOT + tile0 + 2) * 1024 + r * 64 + c] = acc2[j];
        p1[((size_t)q * TILES_TOT + tile0 + 3) * 1024 + r * 64 + c] = acc3[j];
    }
}

// ---------------- combine1: h = relu(sum_q p1 + bc1); y2t = (h @ Wc2)^T bf16 ----------------
__global__ __launch_bounds__(256) void combine1_kernel(
    const float* __restrict__ p1, const float* __restrict__ bc1,
    const float* __restrict__ Wc2g, unsigned short* __restrict__ y2t)
{
    __shared__ float sW[64][32];
    __shared__ float sb[64];
    const int tid = threadIdx.x;
    for (int i = tid; i < 2048; i += 256) sW[i >> 5][i & 31] = Wc2g[i];
    if (tid < 64) sb[tid] = bc1[tid];
    __syncthreads();

    const int pr = blockIdx.x * 64 + (tid & 63);
    const int cq = tid >> 6;
    int m, M, MP; unsigned short* Yo;
    if (pr < 2 * T_SV * 16) {
        int b = pr / (T_SV * 16);
        m = pr - b * (T_SV * 16);
        M = NSV; MP = MP_SV;
        Yo = y2t + (size_t)2 * 32 * MP_SU + (size_t)b * 32 * MP_SV;
    } else {
        int t = pr - 2 * T_SV * 16;
        int b = t / (T_SU * 16);
        m = t - b * (T_SU * 16);
        M = NSU; MP = MP_SU;
        Yo = y2t + (size_t)b * 32 * MP_SU;
    }
    const float* P0 = p1 + (size_t)pr * 64;
    const float* P1 = P0 + (size_t)PADROWS * 64;
    const float* P2 = P1 + (size_t)PADROWS * 64;
    const float* P3 = P2 + (size_t)PADROWS * 64;
    float h[64];
    #pragma unroll
    for (int f4 = 0; f4 < 16; ++f4) {
        float4 u = ((const float4*)P0)[f4];
        float4 v = ((const float4*)P1)[f4];
        float4 w = ((const float4*)P2)[f4];
        float4 z = ((const float4*)P3)[f4];
        h[f4 * 4 + 0] = fmaxf(u.x + v.x + w.x + z.x + sb[f4 * 4 + 0], 0.f);
        h[f4 * 4 + 1] = fmaxf(u.y + v.y + w.y + z.y + sb[f4 * 4 + 1], 0.f);
        h[f4 * 4 + 2] = fmaxf(u.z + v.z + w.z + z.z + sb[f4 * 4 + 2], 0.f);
        h[f4 * 4 + 3] = fmaxf(u.w + v.w + w.w + z.w + sb[f4 * 4 + 3], 0.f);
    }
    float acc[8] = {0.f,0.f,0.f,0.f,0.f,0.f,0.f,0.f};
    #pragma unroll
    for (int f = 0; f < 64; ++f) {
        const float hv = h[f];
        const float4 w0 = *(const float4*)&sW[f][cq * 8];
        const float4 w1 = *(const float4*)&sW[f][cq * 8 + 4];
        acc[0] += hv * w0.x; acc[1] += hv * w0.y; acc[2] += hv * w0.z; acc[3] += hv * w0.w;
        acc[4] += hv * w1.x; acc[5] += hv * w1.y; acc[6] += hv * w1.z; acc[7] += hv * w1.w;
    }
    if (m < M) {
        #pragma unroll
        for (int j = 0; j < 8; ++j)
            Yo[(size_t)(cq * 8 + j) * MP + m] = f2bf(acc[j]);
    }
}

// ---------------- conv2 partial: p2[q][tile][16][32], dense fragment-layout A read ------
__global__ __launch_bounds__(256) void conv2p_kernel(
    const unsigned short* __restrict__ abft,
    const unsigned short* __restrict__ y2t,
    float* __restrict__ p2)
{
    const int bid = blockIdx.x;
    const int q = blockIdx.y;
    const int tid = threadIdx.x, lane = tid & 63, wid = tid >> 6;
    int MP, tile0, KQ, MPE;
    const unsigned short* Yt; const unsigned short* Atl;
    if (bid < 2 * NB64_SV) {
        int b = bid / NB64_SV, rb = bid - b * NB64_SV;
        MP = MP_SV; KQ = KQ_SV; MPE = MP_SV;
        Yt = y2t + (size_t)2 * 32 * MP_SU + (size_t)b * 32 * MP_SV;
        tile0 = b * T_SV + rb * 4;
        Atl = abft + (size_t)(tile0 + wid) * TSZ_SV;
    } else {
        int t = bid - 2 * NB64_SV;
        int b = t / NB64_SU, rb = t - b * NB64_SU;
        MP = MP_SU; KQ = KQ_SU; MPE = MP_SU;
        Yt = y2t + (size_t)b * 32 * MP_SU;
        int tsu = b * T_SU + rb * 4;
        tile0 = 2 * T_SV + tsu;
        Atl = abft + SU_BASE_E + (size_t)(tsu + wid) * TSZ_SU;
    }
    const int cbeg = (q * KQ) >> 6;
    const int cend = (q < NH - 1) ? ((q + 1) * KQ) >> 6 : (MPE >> 6);

    const int l15 = lane & 15, kq = lane >> 4;
    const unsigned short* Apl = Atl + (size_t)lane * 8;
    const unsigned short* Bp  = Yt + (size_t)l15 * MP + kq * 8;
    const size_t MPg = (size_t)16 * MP;

    f32x4 acc0 = {0.f,0.f,0.f,0.f}, acc1 = acc0;

    bf16x8 aa0, aa1, cc0, cc1;
    bf16x8 b0,b1,b2,b3, d0,d1,d2,d3;

#define LDA(A0,A1,ch) do { \
    A0 = *(const bf16x8*)(Apl + (size_t)(ch) * 1024); \
    A1 = *(const bf16x8*)(Apl + (size_t)(ch) * 1024 + 512); } while (0)
#define LDB2(B0,B1,B2,B3,ch) do { \
    const unsigned short* bb = Bp + (size_t)(ch) * 64; \
    B0 = *(const bf16x8*)(bb); \
    B1 = *(const bf16x8*)(bb + 32); \
    B2 = *(const bf16x8*)(bb + MPg); \
    B3 = *(const bf16x8*)(bb + MPg + 32); } while (0)
#define CMP4(F0,F1,B0,B1,B2,B3) do { \
    acc0 = MFMA16(F0, B0, acc0, 0, 0, 0); \
    acc1 = MFMA16(F0, B2, acc1, 0, 0, 0); \
    acc0 = MFMA16(F1, B1, acc0, 0, 0, 0); \
    acc1 = MFMA16(F1, B3, acc1, 0, 0, 0); } while (0)

    LDA(aa0, aa1, cbeg);
    LDB2(b0,b1,b2,b3, cbeg);
    int ch = cbeg;
    while (ch + 2 <= cend) {
        LDA(cc0, cc1, ch + 1);
        LDB2(d0,d1,d2,d3, ch + 1);
        CMP4(aa0, aa1, b0,b1,b2,b3);
        if (ch + 2 < cend) {
            LDA(aa0, aa1, ch + 2);
            LDB2(b0,b1,b2,b3, ch + 2);
        }
        CMP4(cc0, cc1, d0,d1,d2,d3);
        ch += 2;
    }
    if (ch < cend) {
        CMP4(aa0, aa1, b0,b1,b2,b3);
    }
#undef LDA
#undef LDB2
#undef CMP4

    float* Pp = p2 + ((size_t)q * TILES_TOT + tile0 + wid) * (16 * 32);
    #pragma unroll
    for (int j = 0; j < 4; ++j) {
        const int r = kq * 4 + j;
        Pp[r * 32 +      l15] = acc0[j];
        Pp[r * 32 + 16 + l15] = acc1[j];
    }
}

// ---------------- combine2: part[tile][c] = max_r (sum_q p2 + bc2 + init) ----------------
__global__ __launch_bounds__(256) void combine2_kernel(
    const float* __restrict__ p2, const float* __restrict__ bc2,
    const float* __restrict__ initb, float* __restrict__ part)
{
    const int idx = blockIdx.x * 256 + threadIdx.x;
    if (idx >= TILES_TOT * 32) return;
    const int gt = idx >> 5, c = idx & 31;
    int m0, M; const float* I;
    if (gt < 2 * T_SV) {
        int b = gt / T_SV;
        m0 = (gt - b * T_SV) * 16;
        M = NSV;
        I = initb + (size_t)ROWS_SU * 32 + (size_t)b * NSV * 32;
    } else {
        int t = gt - 2 * T_SV;
        int b = t / T_SU;
        m0 = (t - b * T_SU) * 16;
        M = NSU;
        I = initb + (size_t)b * NSU * 32;
    }
    const float* Q0 = p2 + (size_t)gt * 16 * 32 + c;
    const float* Q1 = Q0 + (size_t)TILES_TOT * 16 * 32;
    const float* Q2 = Q1 + (size_t)TILES_TOT * 16 * 32;
    const float* Q3 = Q2 + (size_t)TILES_TOT * 16 * 32;
    const float bb = bc2[c];
    float mx = NEG_INF;
    #pragma unroll
    for (int r = 0; r < 16; ++r) {
        const int m = m0 + r;
        if (m < M) {
            float v = Q0[r * 32] + Q1[r * 32] + Q2[r * 32] + Q3[r * 32]
                      + bb + I[(size_t)m * 32 + c];
            mx = fmaxf(mx, v);
        }
    }
    part[(size_t)gt * 32 + c] = mx;
}

// ---------------- head: pool-reduce + 4-layer MLP ----------------
__global__ __launch_bounds__(128) void head_kernel(
    const float* __restrict__ part,
    const float* __restrict__ Wfc2, const float* __restrict__ bfc2,
    const float* __restrict__ Wfc3, const float* __restrict__ bfc3,
    const float* __restrict__ Wfc4, const float* __restrict__ bfc4,
    const float* __restrict__ Wfc5, const float* __restrict__ bfc5,
    float* __restrict__ out)
{
    __shared__ float d[2][64];
    __shared__ float t1[2][32];
    __shared__ float t2[2][64];
    __shared__ float t3[2][32];
    const int tid = threadIdx.x;

    if (tid < 64) {
        const int b = tid >> 5, c = tid & 31;
        float m = NEG_INF;
        const float* ps = part + (size_t)(2 * T_SV + b * T_SU) * 32 + c;
        for (int i = 0; i < T_SU; ++i) m = fmaxf(m, ps[(size_t)i * 32]);
        d[b][c] = m;
        float m2 = NEG_INF;
        const float* pv = part + (size_t)b * T_SV * 32 + c;
        for (int i = 0; i < T_SV; ++i) m2 = fmaxf(m2, pv[(size_t)i * 32]);
        d[b][32 + c] = m2;
    }
    __syncthreads();
    if (tid < 64) {
        const int b = tid >> 5, c = tid & 31;
        float acc = bfc2[c];
        for (int f = 0; f < 64; ++f) acc += d[b][f] * Wfc2[f * 32 + c];
        t1[b][c] = fmaxf(acc, 0.f);
    }
    __syncthreads();
    {
        const int b = tid >> 6, c = tid & 63;
        float acc = bfc3[c];
        for (int f = 0; f < 32; ++f) acc += t1[b][f] * Wfc3[f * 64 + c];
        t2[b][c] = fmaxf(acc, 0.f);
    }
    __syncthreads();
    if (tid < 64) {
        const int b = tid >> 5, c = tid & 31;
        float acc = bfc4[c];
        for (int f = 0; f < 64; ++f) acc += t2[b][f] * Wfc4[f * 32 + c];
        t3[b][c] = fmaxf(acc, 0.f);
    }
    __syncthreads();
    if (tid < 2) {
        float acc = bfc5[0];
        for (int f = 0; f < 32; ++f) acc += t3[tid][f] * Wfc5[f];
        out[tid] = acc;
    }
}

extern "C" void kernel_launch(void* const* d_in, const int* in_sizes, int n_in,
                              void* d_out, int out_size, void* d_ws, size_t ws_size,
                              hipStream_t stream)
{
    const float* solute_adj   = (const float*)d_in[0];
    const float* solute_meth  = (const float*)d_in[1];
    const float* solvent_meth = (const float*)d_in[2];
    const float* solvent_adj  = (const float*)d_in[3];
    const float* W_fc1 = (const float*)d_in[4];
    const float* b_fc1 = (const float*)d_in[5];
    const float* W_c1  = (const float*)d_in[6];
    const float* b_c1  = (const float*)d_in[7];
    const float* W_c2  = (const float*)d_in[8];
    const float* b_c2  = (const float*)d_in[9];
    const float* W_fc2 = (const float*)d_in[10];
    const float* b_fc2 = (const float*)d_in[11];
    const float* W_fc3 = (const float*)d_in[12];
    const float* b_fc3 = (const float*)d_in[13];
    const float* W_fc4 = (const float*)d_in[14];
    const float* b_fc4 = (const float*)d_in[15];
    const float* W_fc5 = (const float*)d_in[16];
    const float* b_fc5 = (const float*)d_in[17];
    float* out = (float*)d_out;

    // workspace layout (bytes)
    char* wsb = (char*)d_ws;
    size_t off = 0;
    unsigned short* y1t = (unsigned short*)(wsb + off); off += 2850816;
    unsigned short* y2t = (unsigned short*)(wsb + off); off += 1425408;
    float* initb        = (float*)(wsb + off);          off += 2820096;
    unsigned short* abft = (unsigned short*)(wsb + off);
    off += (SU_BASE_E + (size_t)2 * T_SU * TSZ_SU) * 2;                      // ~339 MB
    float* p1           = (float*)(wsb + off);          off += (size_t)NH * PADROWS * 64 * 4;
    float* p2           = (float*)(wsb + off);          off += (size_t)NH * PADROWS * 32 * 4;
    float* part         = (float*)(wsb + off);          off += (size_t)TILES_TOT * 32 * 4;

    pre_kernel<<<dim3((ROWS_ALL + 255) / 256), dim3(256), 0, stream>>>(
        solute_meth, solvent_meth, W_c1, W_fc1, b_fc1, y1t, initb);

    conv1f_kernel<<<dim3(NBX, NH), dim3(256), 0, stream>>>(
        solute_adj, solvent_adj, y1t, abft, p1);

    combine1_kernel<<<dim3(PADROWS / 64), dim3(256), 0, stream>>>(p1, b_c1, W_c2, y2t);

    conv2p_kernel<<<dim3(NBX, NH), dim3(256), 0, stream>>>(abft, y2t, p2);

    combine2_kernel<<<dim3((TILES_TOT * 32 + 255) / 256), dim3(256), 0, stream>>>(
        p2, b_c2, initb, part);

    head_kernel<<<dim3(1), dim3(128), 0, stream>>>(
        part, W_fc2, b_fc2, W_fc3, b_fc3, W_fc4, b_fc4, W_fc5, b_fc5, out);
}

// Round 9
// 645.452 us; speedup vs baseline: 1.3009x; 1.3009x over previous
//
#include <hip/hip_runtime.h>

#define B_      2
#define NSU     2076
#define NSV     8940
#define ROWS_SU (B_ * NSU)            // 4152
#define ROWS_ALL (B_ * (NSU + NSV))   // 22032
#define MP_SU   2176
#define MP_SV   8960
#define NB64_SV 140                   // 8960/64
#define NB64_SU 33                    // 2112/64
#define KH_SV   4480                  // K-split point (mult of 64)
#define KH_SU   1024
#define T_SV    560                   // 16-row tiles per solvent batch
#define T_SU    132
#define TILES_TOT (2 * T_SV + 2 * T_SU)   // 1384
#define PADROWS (TILES_TOT * 16)          // 22144
#define TSZ_SV  ((size_t)16 * MP_SV)      // 143360 elems (140 k64-chunks x 1024)
#define TSZ_SU  ((size_t)16 * MP_SU)      // 34816 elems (34 chunks)
#define SU_BASE_E ((size_t)2 * T_SV * TSZ_SV)   // 160563200
#define NEG_INF (-3.402823466e38f)

typedef __attribute__((ext_vector_type(8))) short bf16x8;
typedef __attribute__((ext_vector_type(4))) float f32x4;

union BF8 { bf16x8 v; unsigned int u[4]; };

#define MFMA16 __builtin_amdgcn_mfma_f32_16x16x32_bf16

__device__ __forceinline__ unsigned short f2bf(float x) {
    unsigned int u = __float_as_uint(x);
    u += 0x7FFFu + ((u >> 16) & 1u);
    return (unsigned short)(u >> 16);
}
__device__ __forceinline__ unsigned int pkbf(float lo, float hi) {
    unsigned int r;
    asm("v_cvt_pk_bf16_f32 %0, %1, %2" : "=v"(r) : "v"(lo), "v"(hi));
    return r;
}

// ---------------- pre: y1t = (x @ W_c1)^T bf16 ; init = x @ W_fc1 + b_fc1 ----------------
__global__ __launch_bounds__(256) void pre_kernel(
    const float* __restrict__ xsu, const float* __restrict__ xsv,
    const float* __restrict__ Wc1, const float* __restrict__ Wfc1,
    const float* __restrict__ bfc1,
    unsigned short* __restrict__ y1t, float* __restrict__ initb)
{
    __shared__ float sWc1[64 * 64];
    __shared__ float sWfc1[64 * 32];
    __shared__ float sb[32];
    const int tid = threadIdx.x;
    for (int i = tid; i < 64 * 64; i += 256) sWc1[i] = Wc1[i];
    for (int i = tid; i < 64 * 32; i += 256) sWfc1[i] = Wfc1[i];
    if (tid < 32) sb[tid] = bfc1[tid];
    __syncthreads();

    const int rid = blockIdx.x * 256 + tid;
    if (rid >= ROWS_ALL) return;

    const float* xrow; unsigned short* yt; int m; size_t MPl;
    if (rid < ROWS_SU) {
        int b = rid / NSU; m = rid - b * NSU;
        xrow = xsu + (size_t)rid * 64;
        yt = y1t + (size_t)b * 64 * MP_SU; MPl = MP_SU;
    } else {
        int r2 = rid - ROWS_SU;
        int b = r2 / NSV; m = r2 - b * NSV;
        xrow = xsv + (size_t)r2 * 64;
        yt = y1t + (size_t)2 * 64 * MP_SU + (size_t)b * 64 * MP_SV; MPl = MP_SV;
    }

    float xr[64];
    #pragma unroll
    for (int f4 = 0; f4 < 16; ++f4) {
        float4 v = ((const float4*)xrow)[f4];
        xr[f4 * 4 + 0] = v.x; xr[f4 * 4 + 1] = v.y;
        xr[f4 * 4 + 2] = v.z; xr[f4 * 4 + 3] = v.w;
    }
    for (int c = 0; c < 64; ++c) {
        float acc = 0.f;
        #pragma unroll
        for (int f = 0; f < 64; ++f) acc += xr[f] * sWc1[f * 64 + c];
        yt[(size_t)c * MPl + m] = f2bf(acc);
    }
    float* ini = initb + (size_t)rid * 32;
    for (int c = 0; c < 32; ++c) {
        float acc = sb[c];
        #pragma unroll
        for (int f = 0; f < 64; ++f) acc += xr[f] * sWfc1[f * 32 + c];
        ini[c] = acc;
    }
}

// ---------------- conv1 partial + fragment-major bf16 adjacency writeback ----------------
// Identical to the R3 (636us, passing) conv1p, plus: after each CVT, the wave stores its
// two bf16 fragments to abft in fragment-major layout [tile][k64][2][64 lanes][8] —
// 64 lanes x 16B = two contiguous 1KB lines per k64, fire-and-forget.
__global__ __launch_bounds__(256) void conv1p_kernel(
    const float* __restrict__ adj_su, const float* __restrict__ adj_sv,
    const unsigned short* __restrict__ y1t,
    unsigned short* __restrict__ abft,
    float* __restrict__ p1)
{
    const int bid = blockIdx.x;
    const int half = blockIdx.y;
    const int tid = threadIdx.x, lane = tid & 63, wid = tid >> 6;
    int M, MP, row0, tile0, KH;
    const float* A; const unsigned short* Yt; unsigned short* AbT;
    if (bid < 2 * NB64_SV) {
        int b = bid / NB64_SV, rb = bid - b * NB64_SV;
        M = NSV; MP = MP_SV; KH = KH_SV;
        A  = adj_sv + (size_t)b * NSV * NSV;
        Yt = y1t + (size_t)2 * 64 * MP_SU + (size_t)b * 64 * MP_SV;
        row0 = rb * 64; tile0 = b * T_SV + rb * 4;
        AbT = abft + (size_t)(tile0 + wid) * TSZ_SV;
    } else {
        int t = bid - 2 * NB64_SV;
        int b = t / NB64_SU, rb = t - b * NB64_SU;
        M = NSU; MP = MP_SU; KH = KH_SU;
        A  = adj_su + (size_t)b * NSU * NSU;
        Yt = y1t + (size_t)b * 64 * MP_SU;
        row0 = rb * 64;
        int tsu = b * T_SU + rb * 4;
        tile0 = 2 * T_SV + tsu;
        AbT = abft + SU_BASE_E + (size_t)(tsu + wid) * TSZ_SU;
    }
    const int kbeg = half ? KH : 0;
    const int kend = half ? M  : KH;

    const int l15 = lane & 15, kq = lane >> 4;
    const int gr  = row0 + wid * 16 + l15;
    const int grc = (gr < M) ? gr : (M - 1);
    const float* Ap  = A + (size_t)grc * M;
    const float* Apk = Ap + kq * 8;
    const unsigned short* Bp = Yt + (size_t)l15 * MP + kq * 8;
    const size_t MPg = (size_t)16 * MP;

    f32x4 acc0 = {0.f,0.f,0.f,0.f}, acc1 = acc0, acc2 = acc0, acc3 = acc0;

    float4 a0,a1,a2,a3, c0,c1,c2,c3;
    bf16x8 b0,b1,b2,b3,b4,b5,b6,b7, d0,d1,d2,d3,d4,d5,d6,d7;

#define LDA(A0,A1,A2,A3,kc) do { \
    A0 = *(const float4*)(Apk + (kc)); \
    A1 = *(const float4*)(Apk + (kc) + 4); \
    A2 = *(const float4*)(Apk + (kc) + 32); \
    A3 = *(const float4*)(Apk + (kc) + 36); } while (0)
#define LDB(B0,B1,B2,B3,B4,B5,B6,B7,kc) do { \
    B0 = *(const bf16x8*)(Bp + (kc)); \
    B1 = *(const bf16x8*)(Bp + (kc) + 32); \
    B2 = *(const bf16x8*)(Bp + MPg + (kc)); \
    B3 = *(const bf16x8*)(Bp + MPg + (kc) + 32); \
    B4 = *(const bf16x8*)(Bp + 2 * MPg + (kc)); \
    B5 = *(const bf16x8*)(Bp + 2 * MPg + (kc) + 32); \
    B6 = *(const bf16x8*)(Bp + 3 * MPg + (kc)); \
    B7 = *(const bf16x8*)(Bp + 3 * MPg + (kc) + 32); } while (0)
#define CVT(F0,F1,A0,A1,A2,A3) do { \
    F0.u[0] = pkbf(A0.x, A0.y); F0.u[1] = pkbf(A0.z, A0.w); \
    F0.u[2] = pkbf(A1.x, A1.y); F0.u[3] = pkbf(A1.z, A1.w); \
    F1.u[0] = pkbf(A2.x, A2.y); F1.u[1] = pkbf(A2.z, A2.w); \
    F1.u[2] = pkbf(A3.x, A3.y); F1.u[3] = pkbf(A3.z, A3.w); } while (0)
#define STFR(F0,F1,kc) do { \
    unsigned short* sp_ = AbT + ((size_t)((kc) >> 6)) * 1024 + lane * 8; \
    *(bf16x8*)sp_ = F0.v; \
    *(bf16x8*)(sp_ + 512) = F1.v; } while (0)
#define CMP8(F0,F1,B0,B1,B2,B3,B4,B5,B6,B7) do { \
    acc0 = MFMA16(F0.v, B0, acc0, 0, 0, 0); \
    acc1 = MFMA16(F0.v, B2, acc1, 0, 0, 0); \
    acc2 = MFMA16(F0.v, B4, acc2, 0, 0, 0); \
    acc3 = MFMA16(F0.v, B6, acc3, 0, 0, 0); \
    acc0 = MFMA16(F1.v, B1, acc0, 0, 0, 0); \
    acc1 = MFMA16(F1.v, B3, acc1, 0, 0, 0); \
    acc2 = MFMA16(F1.v, B5, acc2, 0, 0, 0); \
    acc3 = MFMA16(F1.v, B7, acc3, 0, 0, 0); } while (0)

    const int klast = kbeg + ((kend - kbeg) & ~63);
    if (klast > kbeg) {
        LDA(a0,a1,a2,a3, kbeg);
        LDB(b0,b1,b2,b3,b4,b5,b6,b7, kbeg);
        int kc = kbeg;
        while (kc + 128 <= klast) {
            LDA(c0,c1,c2,c3, kc + 64);
            LDB(d0,d1,d2,d3,d4,d5,d6,d7, kc + 64);
            { BF8 f0, f1; CVT(f0,f1,a0,a1,a2,a3); STFR(f0,f1,kc);
              CMP8(f0,f1,b0,b1,b2,b3,b4,b5,b6,b7); }
            if (kc + 128 < klast) {
                LDA(a0,a1,a2,a3, kc + 128);
                LDB(b0,b1,b2,b3,b4,b5,b6,b7, kc + 128);
            }
            { BF8 f0, f1; CVT(f0,f1,c0,c1,c2,c3); STFR(f0,f1,kc + 64);
              CMP8(f0,f1,d0,d1,d2,d3,d4,d5,d6,d7); }
            kc += 128;
        }
        if (kc < klast) {
            BF8 f0, f1; CVT(f0,f1,a0,a1,a2,a3); STFR(f0,f1,kc);
            CMP8(f0,f1,b0,b1,b2,b3,b4,b5,b6,b7);
        }
    }
    if (klast < kend) {   // guarded tail (< 64 real cols, zero-padded to 64)
        BF8 f0, f1;
        #pragma unroll
        for (int e = 0; e < 8; e += 2) {
            const int ka = klast + kq * 8 + e;
            const float x0 = (ka      < kend) ? Ap[ka]      : 0.f;
            const float x1 = (ka + 1  < kend) ? Ap[ka + 1]  : 0.f;
            const float y0 = (ka + 32 < kend) ? Ap[ka + 32] : 0.f;
            const float y1 = (ka + 33 < kend) ? Ap[ka + 33] : 0.f;
            f0.u[e >> 1] = pkbf(x0, x1);
            f1.u[e >> 1] = pkbf(y0, y1);
        }
        STFR(f0,f1,klast);
        LDB(b0,b1,b2,b3,b4,b5,b6,b7, klast);
        CMP8(f0,f1,b0,b1,b2,b3,b4,b5,b6,b7);
    }
#undef LDA
#undef LDB
#undef CVT
#undef STFR
#undef CMP8

    float* Pp = p1 + ((size_t)half * TILES_TOT + tile0 + wid) * (16 * 64);
    #pragma unroll
    for (int j = 0; j < 4; ++j) {
        const int r = kq * 4 + j;
        Pp[r * 64 +      l15] = acc0[j];
        Pp[r * 64 + 16 + l15] = acc1[j];
        Pp[r * 64 + 32 + l15] = acc2[j];
        Pp[r * 64 + 48 + l15] = acc3[j];
    }
}

// ---------------- combine1: h = relu(p0+p1+bc1); y2t = (h @ Wc2)^T bf16 ----------------
__global__ __launch_bounds__(256) void combine1_kernel(
    const float* __restrict__ p1, const float* __restrict__ bc1,
    const float* __restrict__ Wc2g, unsigned short* __restrict__ y2t)
{
    __shared__ float sW[64][32];
    __shared__ float sb[64];
    const int tid = threadIdx.x;
    for (int i = tid; i < 2048; i += 256) sW[i >> 5][i & 31] = Wc2g[i];
    if (tid < 64) sb[tid] = bc1[tid];
    __syncthreads();

    const int pr = blockIdx.x * 64 + (tid & 63);
    const int cq = tid >> 6;
    int m, M, MP; unsigned short* Yo;
    if (pr < 2 * T_SV * 16) {
        int b = pr / (T_SV * 16);
        m = pr - b * (T_SV * 16);
        M = NSV; MP = MP_SV;
        Yo = y2t + (size_t)2 * 32 * MP_SU + (size_t)b * 32 * MP_SV;
    } else {
        int t = pr - 2 * T_SV * 16;
        int b = t / (T_SU * 16);
        m = t - b * (T_SU * 16);
        M = NSU; MP = MP_SU;
        Yo = y2t + (size_t)b * 32 * MP_SU;
    }
    const float* P0 = p1 + (size_t)pr * 64;
    const float* P1 = P0 + (size_t)PADROWS * 64;
    float h[64];
    #pragma unroll
    for (int f4 = 0; f4 < 16; ++f4) {
        float4 u = ((const float4*)P0)[f4];
        float4 v = ((const float4*)P1)[f4];
        h[f4 * 4 + 0] = fmaxf(u.x + v.x + sb[f4 * 4 + 0], 0.f);
        h[f4 * 4 + 1] = fmaxf(u.y + v.y + sb[f4 * 4 + 1], 0.f);
        h[f4 * 4 + 2] = fmaxf(u.z + v.z + sb[f4 * 4 + 2], 0.f);
        h[f4 * 4 + 3] = fmaxf(u.w + v.w + sb[f4 * 4 + 3], 0.f);
    }
    float acc[8] = {0.f,0.f,0.f,0.f,0.f,0.f,0.f,0.f};
    #pragma unroll
    for (int f = 0; f < 64; ++f) {
        const float hv = h[f];
        const float4 w0 = *(const float4*)&sW[f][cq * 8];
        const float4 w1 = *(const float4*)&sW[f][cq * 8 + 4];
        acc[0] += hv * w0.x; acc[1] += hv * w0.y; acc[2] += hv * w0.z; acc[3] += hv * w0.w;
        acc[4] += hv * w1.x; acc[5] += hv * w1.y; acc[6] += hv * w1.z; acc[7] += hv * w1.w;
    }
    if (m < M) {
        #pragma unroll
        for (int j = 0; j < 8; ++j)
            Yo[(size_t)(cq * 8 + j) * MP + m] = f2bf(acc[j]);
    }
}

// ---------------- conv2 partial: dense fragment-major bf16 A reads, no CVT --------------
__global__ __launch_bounds__(256) void conv2p_kernel(
    const unsigned short* __restrict__ abft,
    const unsigned short* __restrict__ y2t,
    float* __restrict__ p2)
{
    const int bid = blockIdx.x;
    const int half = blockIdx.y;
    const int tid = threadIdx.x, lane = tid & 63, wid = tid >> 6;
    int MP, tile0, cbeg, cend;
    const unsigned short* Yt; const unsigned short* AbT;
    if (bid < 2 * NB64_SV) {
        int b = bid / NB64_SV, rb = bid - b * NB64_SV;
        MP = MP_SV;
        Yt = y2t + (size_t)2 * 32 * MP_SU + (size_t)b * 32 * MP_SV;
        tile0 = b * T_SV + rb * 4;
        AbT = abft + (size_t)(tile0 + wid) * TSZ_SV;
        cbeg = half ? (KH_SV >> 6) : 0;
        cend = half ? 140 : (KH_SV >> 6);       // chunks 0..139 all written by conv1p
    } else {
        int t = bid - 2 * NB64_SV;
        int b = t / NB64_SU, rb = t - b * NB64_SU;
        MP = MP_SU;
        Yt = y2t + (size_t)b * 32 * MP_SU;
        int tsu = b * T_SU + rb * 4;
        tile0 = 2 * T_SV + tsu;
        AbT = abft + SU_BASE_E + (size_t)(tsu + wid) * TSZ_SU;
        cbeg = half ? (KH_SU >> 6) : 0;
        cend = half ? 33 : (KH_SU >> 6);        // chunk 33 unwritten -> skip (all-pad)
    }

    const int l15 = lane & 15, kq = lane >> 4;
    const unsigned short* Apl = AbT + (size_t)lane * 8;
    const unsigned short* Bp  = Yt + (size_t)l15 * MP + kq * 8;
    const size_t MPg = (size_t)16 * MP;

    f32x4 acc0 = {0.f,0.f,0.f,0.f}, acc1 = acc0;

    bf16x8 fa0, fa1, fc0, fc1;
    bf16x8 b0,b1,b2,b3, d0,d1,d2,d3;

#define LDA2(F0,F1,ch) do { \
    F0 = *(const bf16x8*)(Apl + (size_t)(ch) * 1024); \
    F1 = *(const bf16x8*)(Apl + (size_t)(ch) * 1024 + 512); } while (0)
#define LDB2(B0,B1,B2,B3,ch) do { \
    const unsigned short* bb = Bp + (size_t)(ch) * 64; \
    B0 = *(const bf16x8*)(bb); \
    B1 = *(const bf16x8*)(bb + 32); \
    B2 = *(const bf16x8*)(bb + MPg); \
    B3 = *(const bf16x8*)(bb + MPg + 32); } while (0)
#define CMP4(F0,F1,B0,B1,B2,B3) do { \
    acc0 = MFMA16(F0, B0, acc0, 0, 0, 0); \
    acc1 = MFMA16(F0, B2, acc1, 0, 0, 0); \
    acc0 = MFMA16(F1, B1, acc0, 0, 0, 0); \
    acc1 = MFMA16(F1, B3, acc1, 0, 0, 0); } while (0)

    LDA2(fa0, fa1, cbeg);
    LDB2(b0,b1,b2,b3, cbeg);
    int ch = cbeg;
    while (ch + 2 <= cend) {
        LDA2(fc0, fc1, ch + 1);
        LDB2(d0,d1,d2,d3, ch + 1);
        CMP4(fa0, fa1, b0,b1,b2,b3);
        if (ch + 2 < cend) {
            LDA2(fa0, fa1, ch + 2);
            LDB2(b0,b1,b2,b3, ch + 2);
        }
        CMP4(fc0, fc1, d0,d1,d2,d3);
        ch += 2;
    }
    if (ch < cend) {
        CMP4(fa0, fa1, b0,b1,b2,b3);
    }
#undef LDA2
#undef LDB2
#undef CMP4

    float* Pp = p2 + ((size_t)half * TILES_TOT + tile0 + wid) * (16 * 32);
    #pragma unroll
    for (int j = 0; j < 4; ++j) {
        const int r = kq * 4 + j;
        Pp[r * 32 +      l15] = acc0[j];
        Pp[r * 32 + 16 + l15] = acc1[j];
    }
}

// ---------------- combine2: part[tile][c] = max_r (p0+p1+bc2+init) ----------------
__global__ __launch_bounds__(256) void combine2_kernel(
    const float* __restrict__ p2, const float* __restrict__ bc2,
    const float* __restrict__ initb, float* __restrict__ part)
{
    const int idx = blockIdx.x * 256 + threadIdx.x;
    if (idx >= TILES_TOT * 32) return;
    const int gt = idx >> 5, c = idx & 31;
    int m0, M; const float* I;
    if (gt < 2 * T_SV) {
        int b = gt / T_SV;
        m0 = (gt - b * T_SV) * 16;
        M = NSV;
        I = initb + (size_t)ROWS_SU * 32 + (size_t)b * NSV * 32;
    } else {
        int t = gt - 2 * T_SV;
        int b = t / T_SU;
        m0 = (t - b * T_SU) * 16;
        M = NSU;
        I = initb + (size_t)b * NSU * 32;
    }
    const float* Q0 = p2 + (size_t)gt * 16 * 32 + c;
    const float* Q1 = Q0 + (size_t)TILES_TOT * 16 * 32;
    const float bb = bc2[c];
    float mx = NEG_INF;
    #pragma unroll
    for (int r = 0; r < 16; ++r) {
        const int m = m0 + r;
        if (m < M) {
            float v = Q0[r * 32] + Q1[r * 32] + bb + I[(size_t)m * 32 + c];
            mx = fmaxf(mx, v);
        }
    }
    part[(size_t)gt * 32 + c] = mx;
}

// ---------------- head: pool-reduce + 4-layer MLP ----------------
__global__ __launch_bounds__(128) void head_kernel(
    const float* __restrict__ part,
    const float* __restrict__ Wfc2, const float* __restrict__ bfc2,
    const float* __restrict__ Wfc3, const float* __restrict__ bfc3,
    const float* __restrict__ Wfc4, const float* __restrict__ bfc4,
    const float* __restrict__ Wfc5, const float* __restrict__ bfc5,
    float* __restrict__ out)
{
    __shared__ float d[2][64];
    __shared__ float t1[2][32];
    __shared__ float t2[2][64];
    __shared__ float t3[2][32];
    const int tid = threadIdx.x;

    if (tid < 64) {
        const int b = tid >> 5, c = tid & 31;
        float m = NEG_INF;
        const float* ps = part + (size_t)(2 * T_SV + b * T_SU) * 32 + c;
        for (int i = 0; i < T_SU; ++i) m = fmaxf(m, ps[(size_t)i * 32]);
        d[b][c] = m;
        float m2 = NEG_INF;
        const float* pv = part + (size_t)b * T_SV * 32 + c;
        for (int i = 0; i < T_SV; ++i) m2 = fmaxf(m2, pv[(size_t)i * 32]);
        d[b][32 + c] = m2;
    }
    __syncthreads();
    if (tid < 64) {
        const int b = tid >> 5, c = tid & 31;
        float acc = bfc2[c];
        for (int f = 0; f < 64; ++f) acc += d[b][f] * Wfc2[f * 32 + c];
        t1[b][c] = fmaxf(acc, 0.f);
    }
    __syncthreads();
    {
        const int b = tid >> 6, c = tid & 63;
        float acc = bfc3[c];
        for (int f = 0; f < 32; ++f) acc += t1[b][f] * Wfc3[f * 64 + c];
        t2[b][c] = fmaxf(acc, 0.f);
    }
    __syncthreads();
    if (tid < 64) {
        const int b = tid >> 5, c = tid & 31;
        float acc = bfc4[c];
        for (int f = 0; f < 64; ++f) acc += t2[b][f] * Wfc4[f * 32 + c];
        t3[b][c] = fmaxf(acc, 0.f);
    }
    __syncthreads();
    if (tid < 2) {
        float acc = bfc5[0];
        for (int f = 0; f < 32; ++f) acc += t3[tid][f] * Wfc5[f];
        out[tid] = acc;
    }
}

extern "C" void kernel_launch(void* const* d_in, const int* in_sizes, int n_in,
                              void* d_out, int out_size, void* d_ws, size_t ws_size,
                              hipStream_t stream)
{
    const float* solute_adj   = (const float*)d_in[0];
    const float* solute_meth  = (const float*)d_in[1];
    const float* solvent_meth = (const float*)d_in[2];
    const float* solvent_adj  = (const float*)d_in[3];
    const float* W_fc1 = (const float*)d_in[4];
    const float* b_fc1 = (const float*)d_in[5];
    const float* W_c1  = (const float*)d_in[6];
    const float* b_c1  = (const float*)d_in[7];
    const float* W_c2  = (const float*)d_in[8];
    const float* b_c2  = (const float*)d_in[9];
    const float* W_fc2 = (const float*)d_in[10];
    const float* b_fc2 = (const float*)d_in[11];
    const float* W_fc3 = (const float*)d_in[12];
    const float* b_fc3 = (const float*)d_in[13];
    const float* W_fc4 = (const float*)d_in[14];
    const float* b_fc4 = (const float*)d_in[15];
    const float* W_fc5 = (const float*)d_in[16];
    const float* b_fc5 = (const float*)d_in[17];
    float* out = (float*)d_out;

    // workspace layout (bytes) — ~364 MB total
    char* wsb = (char*)d_ws;
    size_t off = 0;
    unsigned short* y1t = (unsigned short*)(wsb + off); off += 2850816;
    unsigned short* y2t = (unsigned short*)(wsb + off); off += 1425408;
    float* initb        = (float*)(wsb + off);          off += 2820096;
    unsigned short* abft = (unsigned short*)(wsb + off);
    off += (SU_BASE_E + (size_t)2 * T_SU * TSZ_SU) * 2;                      // 339.5 MB
    float* p1           = (float*)(wsb + off);          off += (size_t)2 * PADROWS * 64 * 4;
    float* p2           = (float*)(wsb + off);          off += (size_t)2 * PADROWS * 32 * 4;
    float* part         = (float*)(wsb + off);          off += (size_t)TILES_TOT * 32 * 4;

    pre_kernel<<<dim3((ROWS_ALL + 255) / 256), dim3(256), 0, stream>>>(
        solute_meth, solvent_meth, W_c1, W_fc1, b_fc1, y1t, initb);

    dim3 gconv(2 * NB64_SV + 2 * NB64_SU, 2);   // (346, 2)
    conv1p_kernel<<<gconv, dim3(256), 0, stream>>>(solute_adj, solvent_adj, y1t, abft, p1);

    combine1_kernel<<<dim3(PADROWS / 64), dim3(256), 0, stream>>>(p1, b_c1, W_c2, y2t);

    conv2p_kernel<<<gconv, dim3(256), 0, stream>>>(abft, y2t, p2);

    combine2_kernel<<<dim3((TILES_TOT * 32 + 255) / 256), dim3(256), 0, stream>>>(
        p2, b_c2, initb, part);

    head_kernel<<<dim3(1), dim3(128), 0, stream>>>(
        part, W_fc2, b_fc2, W_fc3, b_fc3, W_fc4, b_fc4, W_fc5, b_fc5, out);
}

// Round 10
// 600.991 us; speedup vs baseline: 1.3971x; 1.0740x over previous
//
#include <hip/hip_runtime.h>

#define B_      2
#define NSU     2076
#define NSV     8940
#define ROWS_SU (B_ * NSU)            // 4152
#define ROWS_ALL (B_ * (NSU + NSV))   // 22032
#define MP_SU   2176
#define MP_SV   8960
#define NB64_SV 140                   // 8960/64
#define NB64_SU 33                    // 2112/64
#define NH1     4                     // conv1 K-split
#define NH2     8                     // conv2 K-split
#define KQ_SV   2240                  // conv1 k-cols per quarter (64-mult)
#define KQ_SU   512
#define NCH_SV  140                   // abft chunks per sv tile
#define NCH_SU  33                    // written chunks per su tile (34th is pad, skipped)
#define T_SV    560                   // 16-row tiles per solvent batch
#define T_SU    132
#define TILES_TOT (2 * T_SV + 2 * T_SU)   // 1384
#define PADROWS (TILES_TOT * 16)          // 22144
#define TSZ_SV  ((size_t)16 * MP_SV)      // 143360 elems (140 k64-chunks x 1024)
#define TSZ_SU  ((size_t)16 * MP_SU)      // 34816 elems (34 chunks)
#define SU_BASE_E ((size_t)2 * T_SV * TSZ_SV)   // 160563200
#define NEG_INF (-3.402823466e38f)

typedef __attribute__((ext_vector_type(8))) short bf16x8;
typedef __attribute__((ext_vector_type(4))) float f32x4;

union BF8 { bf16x8 v; unsigned int u[4]; };

#define MFMA16 __builtin_amdgcn_mfma_f32_16x16x32_bf16

__device__ __forceinline__ unsigned short f2bf(float x) {
    unsigned int u = __float_as_uint(x);
    u += 0x7FFFu + ((u >> 16) & 1u);
    return (unsigned short)(u >> 16);
}
__device__ __forceinline__ unsigned int pkbf(float lo, float hi) {
    unsigned int r;
    asm("v_cvt_pk_bf16_f32 %0, %1, %2" : "=v"(r) : "v"(lo), "v"(hi));
    return r;
}

// ---------------- pre: y1t = (x @ W_c1)^T bf16 ; init = x @ W_fc1 + b_fc1 ----------------
__global__ __launch_bounds__(256) void pre_kernel(
    const float* __restrict__ xsu, const float* __restrict__ xsv,
    const float* __restrict__ Wc1, const float* __restrict__ Wfc1,
    const float* __restrict__ bfc1,
    unsigned short* __restrict__ y1t, float* __restrict__ initb)
{
    __shared__ float sWc1[64 * 64];
    __shared__ float sWfc1[64 * 32];
    __shared__ float sb[32];
    const int tid = threadIdx.x;
    for (int i = tid; i < 64 * 64; i += 256) sWc1[i] = Wc1[i];
    for (int i = tid; i < 64 * 32; i += 256) sWfc1[i] = Wfc1[i];
    if (tid < 32) sb[tid] = bfc1[tid];
    __syncthreads();

    const int rid = blockIdx.x * 256 + tid;
    if (rid >= ROWS_ALL) return;

    const float* xrow; unsigned short* yt; int m; size_t MPl;
    if (rid < ROWS_SU) {
        int b = rid / NSU; m = rid - b * NSU;
        xrow = xsu + (size_t)rid * 64;
        yt = y1t + (size_t)b * 64 * MP_SU; MPl = MP_SU;
    } else {
        int r2 = rid - ROWS_SU;
        int b = r2 / NSV; m = r2 - b * NSV;
        xrow = xsv + (size_t)r2 * 64;
        yt = y1t + (size_t)2 * 64 * MP_SU + (size_t)b * 64 * MP_SV; MPl = MP_SV;
    }

    float xr[64];
    #pragma unroll
    for (int f4 = 0; f4 < 16; ++f4) {
        float4 v = ((const float4*)xrow)[f4];
        xr[f4 * 4 + 0] = v.x; xr[f4 * 4 + 1] = v.y;
        xr[f4 * 4 + 2] = v.z; xr[f4 * 4 + 3] = v.w;
    }
    for (int c = 0; c < 64; ++c) {
        float acc = 0.f;
        #pragma unroll
        for (int f = 0; f < 64; ++f) acc += xr[f] * sWc1[f * 64 + c];
        yt[(size_t)c * MPl + m] = f2bf(acc);
    }
    float* ini = initb + (size_t)rid * 32;
    for (int c = 0; c < 32; ++c) {
        float acc = sb[c];
        #pragma unroll
        for (int f = 0; f < 64; ++f) acc += xr[f] * sWfc1[f * 32 + c];
        ini[c] = acc;
    }
}

// ---------------- conv1 partial + fragment-major bf16 adjacency writeback ----------------
// R9 structure, K-split deepened to 4 (blockIdx.y) for 2x waves/CU.
__global__ __launch_bounds__(256) void conv1p_kernel(
    const float* __restrict__ adj_su, const float* __restrict__ adj_sv,
    const unsigned short* __restrict__ y1t,
    unsigned short* __restrict__ abft,
    float* __restrict__ p1)
{
    const int bid = blockIdx.x;
    const int q = blockIdx.y;
    const int tid = threadIdx.x, lane = tid & 63, wid = tid >> 6;
    int M, MP, row0, tile0, KQ;
    const float* A; const unsigned short* Yt; unsigned short* AbT;
    if (bid < 2 * NB64_SV) {
        int b = bid / NB64_SV, rb = bid - b * NB64_SV;
        M = NSV; MP = MP_SV; KQ = KQ_SV;
        A  = adj_sv + (size_t)b * NSV * NSV;
        Yt = y1t + (size_t)2 * 64 * MP_SU + (size_t)b * 64 * MP_SV;
        row0 = rb * 64; tile0 = b * T_SV + rb * 4;
        AbT = abft + (size_t)(tile0 + wid) * TSZ_SV;
    } else {
        int t = bid - 2 * NB64_SV;
        int b = t / NB64_SU, rb = t - b * NB64_SU;
        M = NSU; MP = MP_SU; KQ = KQ_SU;
        A  = adj_su + (size_t)b * NSU * NSU;
        Yt = y1t + (size_t)b * 64 * MP_SU;
        row0 = rb * 64;
        int tsu = b * T_SU + rb * 4;
        tile0 = 2 * T_SV + tsu;
        AbT = abft + SU_BASE_E + (size_t)(tsu + wid) * TSZ_SU;
    }
    const int kbeg = q * KQ;
    const int kend = (q == NH1 - 1) ? M : (kbeg + KQ);

    const int l15 = lane & 15, kq = lane >> 4;
    const int gr  = row0 + wid * 16 + l15;
    const int grc = (gr < M) ? gr : (M - 1);
    const float* Ap  = A + (size_t)grc * M;
    const float* Apk = Ap + kq * 8;
    const unsigned short* Bp = Yt + (size_t)l15 * MP + kq * 8;
    const size_t MPg = (size_t)16 * MP;

    f32x4 acc0 = {0.f,0.f,0.f,0.f}, acc1 = acc0, acc2 = acc0, acc3 = acc0;

    float4 a0,a1,a2,a3, c0,c1,c2,c3;
    bf16x8 b0,b1,b2,b3,b4,b5,b6,b7, d0,d1,d2,d3,d4,d5,d6,d7;

#define LDA(A0,A1,A2,A3,kc) do { \
    A0 = *(const float4*)(Apk + (kc)); \
    A1 = *(const float4*)(Apk + (kc) + 4); \
    A2 = *(const float4*)(Apk + (kc) + 32); \
    A3 = *(const float4*)(Apk + (kc) + 36); } while (0)
#define LDB(B0,B1,B2,B3,B4,B5,B6,B7,kc) do { \
    B0 = *(const bf16x8*)(Bp + (kc)); \
    B1 = *(const bf16x8*)(Bp + (kc) + 32); \
    B2 = *(const bf16x8*)(Bp + MPg + (kc)); \
    B3 = *(const bf16x8*)(Bp + MPg + (kc) + 32); \
    B4 = *(const bf16x8*)(Bp + 2 * MPg + (kc)); \
    B5 = *(const bf16x8*)(Bp + 2 * MPg + (kc) + 32); \
    B6 = *(const bf16x8*)(Bp + 3 * MPg + (kc)); \
    B7 = *(const bf16x8*)(Bp + 3 * MPg + (kc) + 32); } while (0)
#define CVT(F0,F1,A0,A1,A2,A3) do { \
    F0.u[0] = pkbf(A0.x, A0.y); F0.u[1] = pkbf(A0.z, A0.w); \
    F0.u[2] = pkbf(A1.x, A1.y); F0.u[3] = pkbf(A1.z, A1.w); \
    F1.u[0] = pkbf(A2.x, A2.y); F1.u[1] = pkbf(A2.z, A2.w); \
    F1.u[2] = pkbf(A3.x, A3.y); F1.u[3] = pkbf(A3.z, A3.w); } while (0)
#define STFR(F0,F1,kc) do { \
    unsigned short* sp_ = AbT + ((size_t)((kc) >> 6)) * 1024 + lane * 8; \
    *(bf16x8*)sp_ = F0.v; \
    *(bf16x8*)(sp_ + 512) = F1.v; } while (0)
#define CMP8(F0,F1,B0,B1,B2,B3,B4,B5,B6,B7) do { \
    acc0 = MFMA16(F0.v, B0, acc0, 0, 0, 0); \
    acc1 = MFMA16(F0.v, B2, acc1, 0, 0, 0); \
    acc2 = MFMA16(F0.v, B4, acc2, 0, 0, 0); \
    acc3 = MFMA16(F0.v, B6, acc3, 0, 0, 0); \
    acc0 = MFMA16(F1.v, B1, acc0, 0, 0, 0); \
    acc1 = MFMA16(F1.v, B3, acc1, 0, 0, 0); \
    acc2 = MFMA16(F1.v, B5, acc2, 0, 0, 0); \
    acc3 = MFMA16(F1.v, B7, acc3, 0, 0, 0); } while (0)

    const int klast = kbeg + ((kend - kbeg) & ~63);
    if (klast > kbeg) {
        LDA(a0,a1,a2,a3, kbeg);
        LDB(b0,b1,b2,b3,b4,b5,b6,b7, kbeg);
        int kc = kbeg;
        while (kc + 128 <= klast) {
            LDA(c0,c1,c2,c3, kc + 64);
            LDB(d0,d1,d2,d3,d4,d5,d6,d7, kc + 64);
            { BF8 f0, f1; CVT(f0,f1,a0,a1,a2,a3); STFR(f0,f1,kc);
              CMP8(f0,f1,b0,b1,b2,b3,b4,b5,b6,b7); }
            if (kc + 128 < klast) {
                LDA(a0,a1,a2,a3, kc + 128);
                LDB(b0,b1,b2,b3,b4,b5,b6,b7, kc + 128);
            }
            { BF8 f0, f1; CVT(f0,f1,c0,c1,c2,c3); STFR(f0,f1,kc + 64);
              CMP8(f0,f1,d0,d1,d2,d3,d4,d5,d6,d7); }
            kc += 128;
        }
        if (kc < klast) {
            BF8 f0, f1; CVT(f0,f1,a0,a1,a2,a3); STFR(f0,f1,kc);
            CMP8(f0,f1,b0,b1,b2,b3,b4,b5,b6,b7);
        }
    }
    if (klast < kend) {   // guarded tail (< 64 real cols, zero-padded to 64)
        BF8 f0, f1;
        #pragma unroll
        for (int e = 0; e < 8; e += 2) {
            const int ka = klast + kq * 8 + e;
            const float x0 = (ka      < kend) ? Ap[ka]      : 0.f;
            const float x1 = (ka + 1  < kend) ? Ap[ka + 1]  : 0.f;
            const float y0 = (ka + 32 < kend) ? Ap[ka + 32] : 0.f;
            const float y1 = (ka + 33 < kend) ? Ap[ka + 33] : 0.f;
            f0.u[e >> 1] = pkbf(x0, x1);
            f1.u[e >> 1] = pkbf(y0, y1);
        }
        STFR(f0,f1,klast);
        LDB(b0,b1,b2,b3,b4,b5,b6,b7, klast);
        CMP8(f0,f1,b0,b1,b2,b3,b4,b5,b6,b7);
    }
#undef LDA
#undef LDB
#undef CVT
#undef STFR
#undef CMP8

    float* Pp = p1 + ((size_t)q * TILES_TOT + tile0 + wid) * (16 * 64);
    #pragma unroll
    for (int j = 0; j < 4; ++j) {
        const int r = kq * 4 + j;
        Pp[r * 64 +      l15] = acc0[j];
        Pp[r * 64 + 16 + l15] = acc1[j];
        Pp[r * 64 + 32 + l15] = acc2[j];
        Pp[r * 64 + 48 + l15] = acc3[j];
    }
}

// ---------------- combine1: h = relu(sum_q p1 + bc1); y2t = (h @ Wc2)^T bf16 ------------
__global__ __launch_bounds__(256) void combine1_kernel(
    const float* __restrict__ p1, const float* __restrict__ bc1,
    const float* __restrict__ Wc2g, unsigned short* __restrict__ y2t)
{
    __shared__ float sW[64][32];
    __shared__ float sb[64];
    const int tid = threadIdx.x;
    for (int i = tid; i < 2048; i += 256) sW[i >> 5][i & 31] = Wc2g[i];
    if (tid < 64) sb[tid] = bc1[tid];
    __syncthreads();

    const int pr = blockIdx.x * 64 + (tid & 63);
    const int cq = tid >> 6;
    int m, M, MP; unsigned short* Yo;
    if (pr < 2 * T_SV * 16) {
        int b = pr / (T_SV * 16);
        m = pr - b * (T_SV * 16);
        M = NSV; MP = MP_SV;
        Yo = y2t + (size_t)2 * 32 * MP_SU + (size_t)b * 32 * MP_SV;
    } else {
        int t = pr - 2 * T_SV * 16;
        int b = t / (T_SU * 16);
        m = t - b * (T_SU * 16);
        M = NSU; MP = MP_SU;
        Yo = y2t + (size_t)b * 32 * MP_SU;
    }
    const float* P0 = p1 + (size_t)pr * 64;
    const float* P1 = P0 + (size_t)PADROWS * 64;
    const float* P2 = P1 + (size_t)PADROWS * 64;
    const float* P3 = P2 + (size_t)PADROWS * 64;
    float h[64];
    #pragma unroll
    for (int f4 = 0; f4 < 16; ++f4) {
        float4 u = ((const float4*)P0)[f4];
        float4 v = ((const float4*)P1)[f4];
        float4 w = ((const float4*)P2)[f4];
        float4 z = ((const float4*)P3)[f4];
        h[f4 * 4 + 0] = fmaxf(u.x + v.x + w.x + z.x + sb[f4 * 4 + 0], 0.f);
        h[f4 * 4 + 1] = fmaxf(u.y + v.y + w.y + z.y + sb[f4 * 4 + 1], 0.f);
        h[f4 * 4 + 2] = fmaxf(u.z + v.z + w.z + z.z + sb[f4 * 4 + 2], 0.f);
        h[f4 * 4 + 3] = fmaxf(u.w + v.w + w.w + z.w + sb[f4 * 4 + 3], 0.f);
    }
    float acc[8] = {0.f,0.f,0.f,0.f,0.f,0.f,0.f,0.f};
    #pragma unroll
    for (int f = 0; f < 64; ++f) {
        const float hv = h[f];
        const float4 w0 = *(const float4*)&sW[f][cq * 8];
        const float4 w1 = *(const float4*)&sW[f][cq * 8 + 4];
        acc[0] += hv * w0.x; acc[1] += hv * w0.y; acc[2] += hv * w0.z; acc[3] += hv * w0.w;
        acc[4] += hv * w1.x; acc[5] += hv * w1.y; acc[6] += hv * w1.z; acc[7] += hv * w1.w;
    }
    if (m < M) {
        #pragma unroll
        for (int j = 0; j < 8; ++j)
            Yo[(size_t)(cq * 8 + j) * MP + m] = f2bf(acc[j]);
    }
}

// ---------------- conv2 partial: dense fragment-major bf16 A reads, K-split 8 ----------
__global__ __launch_bounds__(256) void conv2p_kernel(
    const unsigned short* __restrict__ abft,
    const unsigned short* __restrict__ y2t,
    float* __restrict__ p2)
{
    const int bid = blockIdx.x;
    const int q = blockIdx.y;
    const int tid = threadIdx.x, lane = tid & 63, wid = tid >> 6;
    int MP, tile0, cbeg, cend;
    const unsigned short* Yt; const unsigned short* AbT;
    if (bid < 2 * NB64_SV) {
        int b = bid / NB64_SV, rb = bid - b * NB64_SV;
        MP = MP_SV;
        Yt = y2t + (size_t)2 * 32 * MP_SU + (size_t)b * 32 * MP_SV;
        tile0 = b * T_SV + rb * 4;
        AbT = abft + (size_t)(tile0 + wid) * TSZ_SV;
        cbeg = (q * NCH_SV) >> 3;
        cend = ((q + 1) * NCH_SV) >> 3;
    } else {
        int t = bid - 2 * NB64_SV;
        int b = t / NB64_SU, rb = t - b * NB64_SU;
        MP = MP_SU;
        Yt = y2t + (size_t)b * 32 * MP_SU;
        int tsu = b * T_SU + rb * 4;
        tile0 = 2 * T_SV + tsu;
        AbT = abft + SU_BASE_E + (size_t)(tsu + wid) * TSZ_SU;
        cbeg = (q * NCH_SU) >> 3;
        cend = ((q + 1) * NCH_SU) >> 3;
    }

    const int l15 = lane & 15, kq = lane >> 4;
    const unsigned short* Apl = AbT + (size_t)lane * 8;
    const unsigned short* Bp  = Yt + (size_t)l15 * MP + kq * 8;
    const size_t MPg = (size_t)16 * MP;

    f32x4 acc0 = {0.f,0.f,0.f,0.f}, acc1 = acc0;

    bf16x8 fa0, fa1, fc0, fc1;
    bf16x8 b0,b1,b2,b3, d0,d1,d2,d3;

#define LDA2(F0,F1,ch) do { \
    F0 = *(const bf16x8*)(Apl + (size_t)(ch) * 1024); \
    F1 = *(const bf16x8*)(Apl + (size_t)(ch) * 1024 + 512); } while (0)
#define LDB2(B0,B1,B2,B3,ch) do { \
    const unsigned short* bb = Bp + (size_t)(ch) * 64; \
    B0 = *(const bf16x8*)(bb); \
    B1 = *(const bf16x8*)(bb + 32); \
    B2 = *(const bf16x8*)(bb + MPg); \
    B3 = *(const bf16x8*)(bb + MPg + 32); } while (0)
#define CMP4(F0,F1,B0,B1,B2,B3) do { \
    acc0 = MFMA16(F0, B0, acc0, 0, 0, 0); \
    acc1 = MFMA16(F0, B2, acc1, 0, 0, 0); \
    acc0 = MFMA16(F1, B1, acc0, 0, 0, 0); \
    acc1 = MFMA16(F1, B3, acc1, 0, 0, 0); } while (0)

    if (cbeg < cend) {
        LDA2(fa0, fa1, cbeg);
        LDB2(b0,b1,b2,b3, cbeg);
        int ch = cbeg;
        while (ch + 2 <= cend) {
            LDA2(fc0, fc1, ch + 1);
            LDB2(d0,d1,d2,d3, ch + 1);
            CMP4(fa0, fa1, b0,b1,b2,b3);
            if (ch + 2 < cend) {
                LDA2(fa0, fa1, ch + 2);
                LDB2(b0,b1,b2,b3, ch + 2);
            }
            CMP4(fc0, fc1, d0,d1,d2,d3);
            ch += 2;
        }
        if (ch < cend) {
            CMP4(fa0, fa1, b0,b1,b2,b3);
        }
    }
#undef LDA2
#undef LDB2
#undef CMP4

    float* Pp = p2 + ((size_t)q * TILES_TOT + tile0 + wid) * (16 * 32);
    #pragma unroll
    for (int j = 0; j < 4; ++j) {
        const int r = kq * 4 + j;
        Pp[r * 32 +      l15] = acc0[j];
        Pp[r * 32 + 16 + l15] = acc1[j];
    }
}

// ---------------- combine2: part[tile][c] = max_r (sum_q p2 + bc2 + init) ----------------
__global__ __launch_bounds__(256) void combine2_kernel(
    const float* __restrict__ p2, const float* __restrict__ bc2,
    const float* __restrict__ initb, float* __restrict__ part)
{
    const int idx = blockIdx.x * 256 + threadIdx.x;
    if (idx >= TILES_TOT * 32) return;
    const int gt = idx >> 5, c = idx & 31;
    int m0, M; const float* I;
    if (gt < 2 * T_SV) {
        int b = gt / T_SV;
        m0 = (gt - b * T_SV) * 16;
        M = NSV;
        I = initb + (size_t)ROWS_SU * 32 + (size_t)b * NSV * 32;
    } else {
        int t = gt - 2 * T_SV;
        int b = t / T_SU;
        m0 = (t - b * T_SU) * 16;
        M = NSU;
        I = initb + (size_t)b * NSU * 32;
    }
    const float* Q = p2 + (size_t)gt * 16 * 32 + c;
    const size_t QS = (size_t)TILES_TOT * 16 * 32;
    const float bb = bc2[c];
    float mx = NEG_INF;
    #pragma unroll
    for (int r = 0; r < 16; ++r) {
        const int m = m0 + r;
        if (m < M) {
            float s = bb + I[(size_t)m * 32 + c];
            #pragma unroll
            for (int qq = 0; qq < NH2; ++qq) s += Q[(size_t)qq * QS + r * 32];
            mx = fmaxf(mx, s);
        }
    }
    part[(size_t)gt * 32 + c] = mx;
}

// ---------------- head: pool-reduce + 4-layer MLP ----------------
__global__ __launch_bounds__(128) void head_kernel(
    const float* __restrict__ part,
    const float* __restrict__ Wfc2, const float* __restrict__ bfc2,
    const float* __restrict__ Wfc3, const float* __restrict__ bfc3,
    const float* __restrict__ Wfc4, const float* __restrict__ bfc4,
    const float* __restrict__ Wfc5, const float* __restrict__ bfc5,
    float* __restrict__ out)
{
    __shared__ float d[2][64];
    __shared__ float t1[2][32];
    __shared__ float t2[2][64];
    __shared__ float t3[2][32];
    const int tid = threadIdx.x;

    if (tid < 64) {
        const int b = tid >> 5, c = tid & 31;
        float m = NEG_INF;
        const float* ps = part + (size_t)(2 * T_SV + b * T_SU) * 32 + c;
        for (int i = 0; i < T_SU; ++i) m = fmaxf(m, ps[(size_t)i * 32]);
        d[b][c] = m;
        float m2 = NEG_INF;
        const float* pv = part + (size_t)b * T_SV * 32 + c;
        for (int i = 0; i < T_SV; ++i) m2 = fmaxf(m2, pv[(size_t)i * 32]);
        d[b][32 + c] = m2;
    }
    __syncthreads();
    if (tid < 64) {
        const int b = tid >> 5, c = tid & 31;
        float acc = bfc2[c];
        for (int f = 0; f < 64; ++f) acc += d[b][f] * Wfc2[f * 32 + c];
        t1[b][c] = fmaxf(acc, 0.f);
    }
    __syncthreads();
    {
        const int b = tid >> 6, c = tid & 63;
        float acc = bfc3[c];
        for (int f = 0; f < 32; ++f) acc += t1[b][f] * Wfc3[f * 64 + c];
        t2[b][c] = fmaxf(acc, 0.f);
    }
    __syncthreads();
    if (tid < 64) {
        const int b = tid >> 5, c = tid & 31;
        float acc = bfc4[c];
        for (int f = 0; f < 64; ++f) acc += t2[b][f] * Wfc4[f * 32 + c];
        t3[b][c] = fmaxf(acc, 0.f);
    }
    __syncthreads();
    if (tid < 2) {
        float acc = bfc5[0];
        for (int f = 0; f < 32; ++f) acc += t3[tid][f] * Wfc5[f];
        out[tid] = acc;
    }
}

extern "C" void kernel_launch(void* const* d_in, const int* in_sizes, int n_in,
                              void* d_out, int out_size, void* d_ws, size_t ws_size,
                              hipStream_t stream)
{
    const float* solute_adj   = (const float*)d_in[0];
    const float* solute_meth  = (const float*)d_in[1];
    const float* solvent_meth = (const float*)d_in[2];
    const float* solvent_adj  = (const float*)d_in[3];
    const float* W_fc1 = (const float*)d_in[4];
    const float* b_fc1 = (const float*)d_in[5];
    const float* W_c1  = (const float*)d_in[6];
    const float* b_c1  = (const float*)d_in[7];
    const float* W_c2  = (const float*)d_in[8];
    const float* b_c2  = (const float*)d_in[9];
    const float* W_fc2 = (const float*)d_in[10];
    const float* b_fc2 = (const float*)d_in[11];
    const float* W_fc3 = (const float*)d_in[12];
    const float* b_fc3 = (const float*)d_in[13];
    const float* W_fc4 = (const float*)d_in[14];
    const float* b_fc4 = (const float*)d_in[15];
    const float* W_fc5 = (const float*)d_in[16];
    const float* b_fc5 = (const float*)d_in[17];
    float* out = (float*)d_out;

    // workspace layout (bytes) — ~392 MB total
    char* wsb = (char*)d_ws;
    size_t off = 0;
    unsigned short* y1t = (unsigned short*)(wsb + off); off += 2850816;
    unsigned short* y2t = (unsigned short*)(wsb + off); off += 1425408;
    float* initb        = (float*)(wsb + off);          off += 2820096;
    unsigned short* abft = (unsigned short*)(wsb + off);
    off += (SU_BASE_E + (size_t)2 * T_SU * TSZ_SU) * 2;                      // 339.5 MB
    float* p1           = (float*)(wsb + off);          off += (size_t)NH1 * PADROWS * 64 * 4; // 22.7 MB
    float* p2           = (float*)(wsb + off);          off += (size_t)NH2 * PADROWS * 32 * 4; // 22.7 MB
    float* part         = (float*)(wsb + off);          off += (size_t)TILES_TOT * 32 * 4;

    pre_kernel<<<dim3((ROWS_ALL + 255) / 256), dim3(256), 0, stream>>>(
        solute_meth, solvent_meth, W_c1, W_fc1, b_fc1, y1t, initb);

    conv1p_kernel<<<dim3(2 * NB64_SV + 2 * NB64_SU, NH1), dim3(256), 0, stream>>>(
        solute_adj, solvent_adj, y1t, abft, p1);

    combine1_kernel<<<dim3(PADROWS / 64), dim3(256), 0, stream>>>(p1, b_c1, W_c2, y2t);

    conv2p_kernel<<<dim3(2 * NB64_SV + 2 * NB64_SU, NH2), dim3(256), 0, stream>>>(
        abft, y2t, p2);

    combine2_kernel<<<dim3((TILES_TOT * 32 + 255) / 256), dim3(256), 0, stream>>>(
        p2, b_c2, initb, part);

    head_kernel<<<dim3(1), dim3(128), 0, stream>>>(
        part, W_fc2, b_fc2, W_fc3, b_fc3, W_fc4, b_fc4, W_fc5, b_fc5, out);
}